// Round 1
// 238.448 us; speedup vs baseline: 1.0320x; 1.0320x over previous
//
#include <hip/hip_runtime.h>

// Problem constants
#define B_    4
#define S_    2048
#define HID_  1024
#define NO_   1024     // NH*HD
#define EPS_  1e-6f
#define M1_   (B_ * S_)   // 8192

typedef __attribute__((ext_vector_type(8))) short  short8;
typedef __attribute__((ext_vector_type(4))) float  f32x4;
typedef unsigned short ushort_t;

__device__ __forceinline__ unsigned short f2bf(float f) {
  union { float f; unsigned int u; } v; v.f = f;
  unsigned int r = v.u + 0x7FFFu + ((v.u >> 16) & 1u);  // RNE
  return (unsigned short)(r >> 16);
}
__device__ __forceinline__ unsigned pack2(float a, float b) {
  return (unsigned)f2bf(a) | ((unsigned)f2bf(b) << 16);
}

// async global->LDS, 16B per lane, dest = wave-uniform base + lane*16
typedef __attribute__((address_space(1))) const void GASV;
typedef __attribute__((address_space(3))) void LASV;
__device__ __forceinline__ void gld16(const void* g, void* l) {
  __builtin_amdgcn_global_load_lds((GASV*)g, (LASV*)l, 16, 0, 0);
}

// ---------------------------------------------------------------------------
// Fused prep: blocks [0,1024)  = WvT transpose+cvt
//             blocks [1024,9216) = Hb = bf16(H)
//             blocks [9216,11264) = Ab = bf16(A * inv_causal_rowsum), masked
// All three are independent memory-bound streams; fusing lets them overlap
// and drops 2 launch gaps.
// ---------------------------------------------------------------------------
__global__ __launch_bounds__(256) void k_prep(
    const float* __restrict__ Wv, ushort_t* __restrict__ WvT,
    const float* __restrict__ H,  ushort_t* __restrict__ Hb,
    const float* __restrict__ A,  ushort_t* __restrict__ Ab) {
  int id = blockIdx.x;
  if (id < 1024) {
    // WvT[n][k] = bf16(Wv[k][n]) via 32x32 LDS tile
    __shared__ float tile[32][33];
    int k0 = (id & 31) * 32;
    int n0 = (id >> 5) * 32;
    int tx = threadIdx.x & 31, ty = threadIdx.x >> 5;   // 32 x 8
    for (int i = ty; i < 32; i += 8)
      tile[i][tx] = Wv[(size_t)(k0 + i) * NO_ + n0 + tx];
    __syncthreads();
    for (int i = ty; i < 32; i += 8)
      WvT[(size_t)(n0 + i) * HID_ + k0 + tx] = f2bf(tile[tx][i]);
  } else if (id < 1024 + 8192) {
    // Hb = bf16(H), 1024 floats per block
    size_t i = ((size_t)(id - 1024) * 256 + threadIdx.x) * 4;
    float4 v = *(const float4*)(H + i);
    uint2 p; p.x = pack2(v.x, v.y); p.y = pack2(v.z, v.w);
    *(uint2*)(Hb + i) = p;
  } else {
    // One wave per row: causal mask, rowsum, scale, cvt. Row in VGPRs.
    int row  = (id - 9216) * 4 + (threadIdx.x >> 6);   // row = b*S + q
    int lane = threadIdx.x & 63;
    int q = row & 2047;
    int wend = ((q >> 7) + 1) << 7;
    const float* rp = A + (size_t)row * S_;
    float4 v[8];
    float s = 0.f;
#pragma unroll
    for (int i = 0; i < 8; i++) {
      int k = i * 256 + lane * 4;
      if (k < wend) {
        float4 t = *(const float4*)(rp + k);
        t.x = (k + 0 <= q) ? t.x : 0.f;
        t.y = (k + 1 <= q) ? t.y : 0.f;
        t.z = (k + 2 <= q) ? t.z : 0.f;
        t.w = (k + 3 <= q) ? t.w : 0.f;
        v[i] = t;
        s += t.x + t.y + t.z + t.w;
      }
    }
    for (int off = 1; off < 64; off <<= 1) s += __shfl_xor(s, off, 64);
    float inv = 1.0f / (EPS_ + s);
    ushort_t* op = Ab + (size_t)row * S_;
#pragma unroll
    for (int i = 0; i < 8; i++) {
      int k = i * 256 + lane * 4;
      if (k < wend) {
        uint2 p;
        p.x = pack2(v[i].x * inv, v[i].y * inv);
        p.y = pack2(v[i].z * inv, v[i].w * inv);
        *(uint2*)(op + k) = p;
      }
    }
  }
}

// ---------------------------------------------------------------------------
// GEMM 1: Vt[b][n][s] = bf16( sum_k WvT[n][k]*Hb[m][k] + bv[n] ), m=b*S+s.
// 128x128 tile (m97 structure), 4 waves each owning a 64x64 quadrant, BK=32.
// grid (64 m-tiles, 8 n-tiles) = 512 blocks -> 2 blocks/CU, 8 waves/CU.
// ---------------------------------------------------------------------------
__global__ __launch_bounds__(256) void k_vt(
    const ushort_t* __restrict__ WvT, const ushort_t* __restrict__ Hb,
    const float* __restrict__ bv, ushort_t* __restrict__ Vt) {
  __shared__ __align__(16) ushort_t lds_a[128 * 32];  // 8 KB, n-rows
  __shared__ __align__(16) ushort_t lds_b[128 * 32];  // 8 KB, m-rows
  int m0 = blockIdx.x * 128;
  int n0 = blockIdx.y * 128;
  int tid = threadIdx.x;
  int wave = tid >> 6, lane = tid & 63;
  int lq = lane >> 4, lm = lane & 15;
  int wr = wave >> 1, wc = wave & 1;     // wave quadrant: (n-half, m-half)

  int rr = lane >> 2;                      // 0..15 row within a 16-row issue
  int sc = (lane & 3) ^ ((rr >> 1) & 3);   // pre-swizzled 16B chunk (src side)
  const ushort_t* gA = WvT + (size_t)(n0 + wave * 32 + rr) * HID_ + sc * 8;
  const ushort_t* gB = Hb  + (size_t)(m0 + wave * 32 + rr) * HID_ + sc * 8;
  char* la = (char*)lds_a;
  char* lb = (char*)lds_b;
  char* la_w = la + wave * 2048;   // 32 rows * 64B per wave
  char* lb_w = lb + wave * 2048;
  int swz = (lm >> 1) & 3;
  int fo = (lq ^ swz) << 4;        // swizzled read offset (same involution)

  f32x4 acc[4][4];
  for (int i = 0; i < 4; i++) for (int j = 0; j < 4; j++) acc[i][j] = (f32x4)0.0f;

  for (int it = 0; it < HID_ / 32; it++) {
    gld16(gA,               la_w);
    gld16(gA + 16 * HID_,   la_w + 1024);
    gld16(gB,               lb_w);
    gld16(gB + 16 * HID_,   lb_w + 1024);
    gA += 32; gB += 32;
    __syncthreads();
    short8 af[4], bfr[4];
#pragma unroll
    for (int mi = 0; mi < 4; mi++)
      af[mi] = *(const short8*)(la + (wr * 64 + mi * 16 + lm) * 64 + fo);
#pragma unroll
    for (int ni = 0; ni < 4; ni++)
      bfr[ni] = *(const short8*)(lb + (wc * 64 + ni * 16 + lm) * 64 + fo);
#pragma unroll
    for (int mi = 0; mi < 4; mi++)
#pragma unroll
      for (int ni = 0; ni < 4; ni++)
        acc[mi][ni] = __builtin_amdgcn_mfma_f32_16x16x32_bf16(af[mi], bfr[ni], acc[mi][ni], 0, 0, 0);
    __syncthreads();
  }
  for (int mi = 0; mi < 4; mi++) {
    for (int r = 0; r < 4; r++) {
      int n = n0 + wr * 64 + mi * 16 + lq * 4 + r;
      float bias = bv[n];
      for (int ni = 0; ni < 4; ni++) {
        int m = m0 + wc * 64 + ni * 16 + lm;
        int b = m >> 11;
        int s = m & 2047;
        Vt[((size_t)b * NO_ + n) * S_ + s] = f2bf(acc[mi][ni][r] + bias);
      }
    }
  }
}

// ---------------------------------------------------------------------------
// GEMM 2: out[b,q,n] = sum_k Ab[b,q,k] * Vt[b,n,k]   (inv pre-applied in Ab)
// 128x128 tile, 4 waves, BK=32. grid (32 cols, 16 y). y->t remap pairs
// complementary causal depths on the same CU: blocks c and c+256 see
// t=15-y and t=y, so every CU runs exactly 68 K-iterations.
// ---------------------------------------------------------------------------
__global__ __launch_bounds__(256) void k_attn(
    const ushort_t* __restrict__ Ab, const ushort_t* __restrict__ Vt,
    float* __restrict__ out) {
  __shared__ __align__(16) ushort_t lds_a[128 * 32];  // 8 KB, q-rows
  __shared__ __align__(16) ushort_t lds_b[128 * 32];  // 8 KB, n-rows
  int col = blockIdx.x;                 // 32 columns: (n-tile, b)
  int n0 = (col & 7) * 128;
  int b  = col >> 3;
  int y  = (int)blockIdx.y;
  int t  = (y < 8) ? (15 - y) : (y - 8);   // complementary pairing
  int q0 = t * 128;
  int tid = threadIdx.x;
  int wave = tid >> 6, lane = tid & 63;
  int lq = lane >> 4, lm = lane & 15;
  int wr = wave >> 1, wc = wave & 1;

  int rr = lane >> 2;
  int sc = (lane & 3) ^ ((rr >> 1) & 3);
  const ushort_t* gA = Ab + ((size_t)(b * S_ + q0 + wave * 32 + rr)) * S_ + sc * 8;
  const ushort_t* gB = Vt + ((size_t)(b * NO_ + n0 + wave * 32 + rr)) * S_ + sc * 8;
  char* la = (char*)lds_a;
  char* lb = (char*)lds_b;
  char* la_w = la + wave * 2048;
  char* lb_w = lb + wave * 2048;
  int swz = (lm >> 1) & 3;
  int fo = (lq ^ swz) << 4;

  f32x4 acc[4][4];
  for (int i = 0; i < 4; i++) for (int j = 0; j < 4; j++) acc[i][j] = (f32x4)0.0f;

  const int iters = 4 * t + 4;          // K = 128*(t+1), BK=32
  for (int it = 0; it < iters; it++) {
    gld16(gA,             la_w);
    gld16(gA + 16 * S_,   la_w + 1024);
    gld16(gB,             lb_w);
    gld16(gB + 16 * S_,   lb_w + 1024);
    gA += 32; gB += 32;
    __syncthreads();
    short8 af[4], bfr[4];
#pragma unroll
    for (int mi = 0; mi < 4; mi++)
      af[mi] = *(const short8*)(la + (wr * 64 + mi * 16 + lm) * 64 + fo);
#pragma unroll
    for (int ni = 0; ni < 4; ni++)
      bfr[ni] = *(const short8*)(lb + (wc * 64 + ni * 16 + lm) * 64 + fo);
#pragma unroll
    for (int mi = 0; mi < 4; mi++)
#pragma unroll
      for (int ni = 0; ni < 4; ni++)
        acc[mi][ni] = __builtin_amdgcn_mfma_f32_16x16x32_bf16(af[mi], bfr[ni], acc[mi][ni], 0, 0, 0);
    __syncthreads();
  }
  for (int mi = 0; mi < 4; mi++) {
    for (int r = 0; r < 4; r++) {
      int q = q0 + wr * 64 + mi * 16 + lq * 4 + r;
      for (int ni = 0; ni < 4; ni++) {
        int n = n0 + wc * 64 + ni * 16 + lm;
        out[((size_t)(b * S_ + q)) * NO_ + n] = acc[mi][ni][r];
      }
    }
  }
}

// ---------------------------------------------------------------------------
extern "C" void kernel_launch(void* const* d_in, const int* in_sizes, int n_in,
                              void* d_out, int out_size, void* d_ws, size_t ws_size,
                              hipStream_t stream) {
  const float* H  = (const float*)d_in[0];   // [B,S,HID]
  const float* A  = (const float*)d_in[1];   // [B,S,S]
  const float* Wv = (const float*)d_in[3];   // [HID, NO]
  const float* bv = (const float*)d_in[4];   // [NO]
  float* out = (float*)d_out;

  char* ws = (char*)d_ws;
  ushort_t* WvT = (ushort_t*)ws;                                  //  2.0 MB
  ushort_t* Hb  = (ushort_t*)(ws + 2097152);                      // 16.8 MB
  ushort_t* Vt  = (ushort_t*)(ws + 2097152 + 16777216);           // 16.8 MB
  ushort_t* Abf = (ushort_t*)(ws + 2097152 + 2 * 16777216);       // 33.6 MB

  k_prep <<<1024 + 8192 + 2048, 256, 0, stream>>>(Wv, WvT, H, Hb, A, Abf);
  k_vt   <<<dim3(M1_ / 128, NO_ / 128), 256, 0, stream>>>(WvT, Hb, bv, Vt);
  k_attn <<<dim3(32, 16), 256, 0, stream>>>(Abf, Vt, out);
}

// Round 2
// 234.961 us; speedup vs baseline: 1.0473x; 1.0148x over previous
//
#include <hip/hip_runtime.h>

// Problem constants
#define B_    4
#define S_    2048
#define HID_  1024
#define NO_   1024     // NH*HD
#define EPS_  1e-6f
#define M1_   (B_ * S_)   // 8192

typedef __attribute__((ext_vector_type(8))) short  short8;
typedef __attribute__((ext_vector_type(4))) float  f32x4;
typedef unsigned short ushort_t;

__device__ __forceinline__ unsigned short f2bf(float f) {
  union { float f; unsigned int u; } v; v.f = f;
  unsigned int r = v.u + 0x7FFFu + ((v.u >> 16) & 1u);  // RNE
  return (unsigned short)(r >> 16);
}
__device__ __forceinline__ unsigned pack2(float a, float b) {
  return (unsigned)f2bf(a) | ((unsigned)f2bf(b) << 16);
}

// async global->LDS, 16B per lane, dest = wave-uniform base + lane*16
typedef __attribute__((address_space(1))) const void GASV;
typedef __attribute__((address_space(3))) void LASV;
__device__ __forceinline__ void gld16(const void* g, void* l) {
  __builtin_amdgcn_global_load_lds((GASV*)g, (LASV*)l, 16, 0, 0);
}

// ---------------------------------------------------------------------------
// Fused prep (unchanged): WvT transpose+cvt | Hb=bf16(H) | Ab=bf16(A*inv)
// ---------------------------------------------------------------------------
__global__ __launch_bounds__(256) void k_prep(
    const float* __restrict__ Wv, ushort_t* __restrict__ WvT,
    const float* __restrict__ H,  ushort_t* __restrict__ Hb,
    const float* __restrict__ A,  ushort_t* __restrict__ Ab) {
  int id = blockIdx.x;
  if (id < 1024) {
    __shared__ float tile[32][33];
    int k0 = (id & 31) * 32;
    int n0 = (id >> 5) * 32;
    int tx = threadIdx.x & 31, ty = threadIdx.x >> 5;   // 32 x 8
    for (int i = ty; i < 32; i += 8)
      tile[i][tx] = Wv[(size_t)(k0 + i) * NO_ + n0 + tx];
    __syncthreads();
    for (int i = ty; i < 32; i += 8)
      WvT[(size_t)(n0 + i) * HID_ + k0 + tx] = f2bf(tile[tx][i]);
  } else if (id < 1024 + 8192) {
    size_t i = ((size_t)(id - 1024) * 256 + threadIdx.x) * 4;
    float4 v = *(const float4*)(H + i);
    uint2 p; p.x = pack2(v.x, v.y); p.y = pack2(v.z, v.w);
    *(uint2*)(Hb + i) = p;
  } else {
    int row  = (id - 9216) * 4 + (threadIdx.x >> 6);   // row = b*S + q
    int lane = threadIdx.x & 63;
    int q = row & 2047;
    int wend = ((q >> 7) + 1) << 7;
    const float* rp = A + (size_t)row * S_;
    float4 v[8];
    float s = 0.f;
#pragma unroll
    for (int i = 0; i < 8; i++) {
      int k = i * 256 + lane * 4;
      if (k < wend) {
        float4 t = *(const float4*)(rp + k);
        t.x = (k + 0 <= q) ? t.x : 0.f;
        t.y = (k + 1 <= q) ? t.y : 0.f;
        t.z = (k + 2 <= q) ? t.z : 0.f;
        t.w = (k + 3 <= q) ? t.w : 0.f;
        v[i] = t;
        s += t.x + t.y + t.z + t.w;
      }
    }
    for (int off = 1; off < 64; off <<= 1) s += __shfl_xor(s, off, 64);
    float inv = 1.0f / (EPS_ + s);
    ushort_t* op = Ab + (size_t)row * S_;
#pragma unroll
    for (int i = 0; i < 8; i++) {
      int k = i * 256 + lane * 4;
      if (k < wend) {
        uint2 p;
        p.x = pack2(v[i].x * inv, v[i].y * inv);
        p.y = pack2(v[i].z * inv, v[i].w * inv);
        *(uint2*)(op + k) = p;
      }
    }
  }
}

// ---------------------------------------------------------------------------
// GEMM 1: Vt[b][n][s] = bf16( sum_k WvT[n][k]*Hb[m][k] + bv[n] ), m=b*S+s.
// 128x128 tile, 4 waves, BK=32. Depth-3 prefetch over a 4-buffer LDS ring:
// iteration i stages tile i+3 and waits vmcnt(12) (tile i's loads issued
// ~3 iters ago). Raw s_barrier (no vmcnt(0) drain). grid 64x8 = 512 blocks.
// ---------------------------------------------------------------------------
__global__ __launch_bounds__(256) void k_vt(
    const ushort_t* __restrict__ WvT, const ushort_t* __restrict__ Hb,
    const float* __restrict__ bv, ushort_t* __restrict__ Vt) {
  __shared__ __align__(16) ushort_t lds_a[4 * 128 * 32];  // 32 KB ring, n-rows
  __shared__ __align__(16) ushort_t lds_b[4 * 128 * 32];  // 32 KB ring, m-rows
  int m0 = blockIdx.x * 128;
  int n0 = blockIdx.y * 128;
  int tid = threadIdx.x;
  int wave = tid >> 6, lane = tid & 63;
  int lq = lane >> 4, lm = lane & 15;
  int wr = wave >> 1, wc = wave & 1;

  int rr = lane >> 2;                      // 0..15 row within a 16-row issue
  int sc = (lane & 3) ^ ((rr >> 1) & 3);   // pre-swizzled 16B chunk (src side)
  const ushort_t* pa = WvT + (size_t)(n0 + wave * 32 + rr) * HID_ + sc * 8;
  const ushort_t* pb = Hb  + (size_t)(m0 + wave * 32 + rr) * HID_ + sc * 8;
  char* la = (char*)lds_a;
  char* lb = (char*)lds_b;
  char* la_w = la + wave * 2048;   // 32 rows * 64B per wave within a buffer
  char* lb_w = lb + wave * 2048;
  int swz = (lm >> 1) & 3;
  int fo = (lq ^ swz) << 4;        // swizzled read offset (same involution)

  auto STAGE = [&](int tile) {
    char* da = la_w + (tile & 3) * 8192;
    char* db = lb_w + (tile & 3) * 8192;
    gld16(pa,             da);
    gld16(pa + 16 * HID_, da + 1024);
    gld16(pb,             db);
    gld16(pb + 16 * HID_, db + 1024);
    pa += 32; pb += 32;
  };

  f32x4 acc[4][4];
  for (int i = 0; i < 4; i++) for (int j = 0; j < 4; j++) acc[i][j] = (f32x4)0.0f;

  const int iters = HID_ / 32;   // 32
  STAGE(0); STAGE(1); STAGE(2);
  for (int it = 0; it < iters; ++it) {
    int rem = iters - 1 - it;
    if (rem >= 3) { STAGE(it + 3); asm volatile("s_waitcnt vmcnt(12)" ::: "memory"); }
    else if (rem == 2) { asm volatile("s_waitcnt vmcnt(8)"  ::: "memory"); }
    else if (rem == 1) { asm volatile("s_waitcnt vmcnt(4)"  ::: "memory"); }
    else               { asm volatile("s_waitcnt vmcnt(0)"  ::: "memory"); }
    __builtin_amdgcn_s_barrier();
    const char* ra = la + (it & 3) * 8192;
    const char* rb = lb + (it & 3) * 8192;
    short8 af[4], bfr[4];
#pragma unroll
    for (int mi = 0; mi < 4; mi++)
      af[mi] = *(const short8*)(ra + (wr * 64 + mi * 16 + lm) * 64 + fo);
#pragma unroll
    for (int ni = 0; ni < 4; ni++)
      bfr[ni] = *(const short8*)(rb + (wc * 64 + ni * 16 + lm) * 64 + fo);
#pragma unroll
    for (int mi = 0; mi < 4; mi++)
#pragma unroll
      for (int ni = 0; ni < 4; ni++)
        acc[mi][ni] = __builtin_amdgcn_mfma_f32_16x16x32_bf16(af[mi], bfr[ni], acc[mi][ni], 0, 0, 0);
    asm volatile("" ::: "memory");
    __builtin_amdgcn_s_barrier();
  }
  for (int mi = 0; mi < 4; mi++) {
    for (int r = 0; r < 4; r++) {
      int n = n0 + wr * 64 + mi * 16 + lq * 4 + r;
      float bias = bv[n];
      for (int ni = 0; ni < 4; ni++) {
        int m = m0 + wc * 64 + ni * 16 + lm;
        int b = m >> 11;
        int s = m & 2047;
        Vt[((size_t)b * NO_ + n) * S_ + s] = f2bf(acc[mi][ni][r] + bias);
      }
    }
  }
}

// ---------------------------------------------------------------------------
// GEMM 2: out[b,q,n] = sum_k Ab[b,q,k] * Vt[b,n,k]   (inv pre-applied in Ab)
// 128x128 tile, 4 waves, BK=32, same depth-3 prefetch ring.
// grid (32, 8) = 256 blocks, 1/CU; each block runs q-tiles t=y and t=15-y
// sequentially -> exactly 68 K-iterations per block (deterministic balance).
// ---------------------------------------------------------------------------
__global__ __launch_bounds__(256) void k_attn(
    const ushort_t* __restrict__ Ab, const ushort_t* __restrict__ Vt,
    float* __restrict__ out) {
  __shared__ __align__(16) ushort_t lds_a[4 * 128 * 32];  // 32 KB ring, q-rows
  __shared__ __align__(16) ushort_t lds_b[4 * 128 * 32];  // 32 KB ring, n-rows
  int col = blockIdx.x;                 // 32 columns: (n-tile, b)
  int n0 = (col & 7) * 128;
  int b  = col >> 3;
  int tid = threadIdx.x;
  int wave = tid >> 6, lane = tid & 63;
  int lq = lane >> 4, lm = lane & 15;
  int wr = wave >> 1, wc = wave & 1;

  int rr = lane >> 2;
  int sc = (lane & 3) ^ ((rr >> 1) & 3);
  char* la = (char*)lds_a;
  char* lb = (char*)lds_b;
  char* la_w = la + wave * 2048;
  char* lb_w = lb + wave * 2048;
  int swz = (lm >> 1) & 3;
  int fo = (lq ^ swz) << 4;

  const ushort_t* gB0 = Vt + ((size_t)(b * NO_ + n0 + wave * 32 + rr)) * S_ + sc * 8;

  for (int seg = 0; seg < 2; ++seg) {
    int t  = (seg == 0) ? (int)blockIdx.y : (15 - (int)blockIdx.y);
    int q0 = t * 128;
    const int iters = 4 * t + 4;        // K = 128*(t+1), BK=32; min 4 >= 3
    const ushort_t* pa = Ab + ((size_t)(b * S_ + q0 + wave * 32 + rr)) * S_ + sc * 8;
    const ushort_t* pb = gB0;

    auto STAGE = [&](int tile) {
      char* da = la_w + (tile & 3) * 8192;
      char* db = lb_w + (tile & 3) * 8192;
      gld16(pa,           da);
      gld16(pa + 16 * S_, da + 1024);
      gld16(pb,           db);
      gld16(pb + 16 * S_, db + 1024);
      pa += 32; pb += 32;
    };

    f32x4 acc[4][4];
    for (int i = 0; i < 4; i++) for (int j = 0; j < 4; j++) acc[i][j] = (f32x4)0.0f;

    STAGE(0); STAGE(1); STAGE(2);
    for (int it = 0; it < iters; ++it) {
      int rem = iters - 1 - it;
      if (rem >= 3) { STAGE(it + 3); asm volatile("s_waitcnt vmcnt(12)" ::: "memory"); }
      else if (rem == 2) { asm volatile("s_waitcnt vmcnt(8)"  ::: "memory"); }
      else if (rem == 1) { asm volatile("s_waitcnt vmcnt(4)"  ::: "memory"); }
      else               { asm volatile("s_waitcnt vmcnt(0)"  ::: "memory"); }
      __builtin_amdgcn_s_barrier();
      const char* ra = la + (it & 3) * 8192;
      const char* rb = lb + (it & 3) * 8192;
      short8 af[4], bfr[4];
#pragma unroll
      for (int mi = 0; mi < 4; mi++)
        af[mi] = *(const short8*)(ra + (wr * 64 + mi * 16 + lm) * 64 + fo);
#pragma unroll
      for (int ni = 0; ni < 4; ni++)
        bfr[ni] = *(const short8*)(rb + (wc * 64 + ni * 16 + lm) * 64 + fo);
#pragma unroll
      for (int mi = 0; mi < 4; mi++)
#pragma unroll
        for (int ni = 0; ni < 4; ni++)
          acc[mi][ni] = __builtin_amdgcn_mfma_f32_16x16x32_bf16(af[mi], bfr[ni], acc[mi][ni], 0, 0, 0);
      asm volatile("" ::: "memory");
      __builtin_amdgcn_s_barrier();
    }
    // epilogue for this q-tile
    for (int mi = 0; mi < 4; mi++) {
      for (int r = 0; r < 4; r++) {
        int q = q0 + wr * 64 + mi * 16 + lq * 4 + r;
        for (int ni = 0; ni < 4; ni++) {
          int n = n0 + wc * 64 + ni * 16 + lm;
          out[((size_t)(b * S_ + q)) * NO_ + n] = acc[mi][ni][r];
        }
      }
    }
    // stores share the vmcnt counter with the next segment's staged loads;
    // drain once per segment boundary so the counted waits stay exact.
    asm volatile("s_waitcnt vmcnt(0)" ::: "memory");
  }
}

// ---------------------------------------------------------------------------
extern "C" void kernel_launch(void* const* d_in, const int* in_sizes, int n_in,
                              void* d_out, int out_size, void* d_ws, size_t ws_size,
                              hipStream_t stream) {
  const float* H  = (const float*)d_in[0];   // [B,S,HID]
  const float* A  = (const float*)d_in[1];   // [B,S,S]
  const float* Wv = (const float*)d_in[3];   // [HID, NO]
  const float* bv = (const float*)d_in[4];   // [NO]
  float* out = (float*)d_out;

  char* ws = (char*)d_ws;
  ushort_t* WvT = (ushort_t*)ws;                                  //  2.0 MB
  ushort_t* Hb  = (ushort_t*)(ws + 2097152);                      // 16.8 MB
  ushort_t* Vt  = (ushort_t*)(ws + 2097152 + 16777216);           // 16.8 MB
  ushort_t* Abf = (ushort_t*)(ws + 2097152 + 2 * 16777216);       // 33.6 MB

  k_prep <<<1024 + 8192 + 2048, 256, 0, stream>>>(Wv, WvT, H, Hb, A, Abf);
  k_vt   <<<dim3(M1_ / 128, NO_ / 128), 256, 0, stream>>>(WvT, Hb, bv, Vt);
  k_attn <<<dim3(32, 8), 256, 0, stream>>>(Abf, Vt, out);
}